// Round 4
// baseline (317.551 us; speedup 1.0000x reference)
//
#include <hip/hip_runtime.h>

typedef unsigned short u16;
typedef __attribute__((ext_vector_type(4))) unsigned short u16x4;
typedef __attribute__((ext_vector_type(8))) unsigned short u16x8;
typedef __attribute__((ext_vector_type(8))) __bf16 bf16x8;
typedef __attribute__((ext_vector_type(4))) float f32x4;

#define S_LEN 2048
#define HDIM 1024
#define NHEAD 16
#define HD 64
#define MTOK 4096            // B*S
#define QKV_STRIDE 4194304   // elements per q/k/v plane
#define LOG2E 1.44269504089f
#define QKSCL (0.125f * 1.44269504089f)

__device__ __forceinline__ float bf2f(u16 h) {
    unsigned u = ((unsigned)h) << 16;
    return __builtin_bit_cast(float, u);
}
__device__ __forceinline__ u16 f2bf(float f) {
    return __builtin_bit_cast(u16, (__bf16)f);   // native v_cvt, RNE
}
__device__ __forceinline__ bf16x8 as_bf16(u16x8 u) {
    union { u16x8 a; bf16x8 b; } c; c.a = u; return c.b;
}
__device__ __forceinline__ void gld_lds16(const u16* g, u16* l) {
    __builtin_amdgcn_global_load_lds((const __attribute__((address_space(1))) u16*)g,
                                     (__attribute__((address_space(3))) u16*)l, 16, 0, 0);
}

// ---------------- fused preprocessing: casts + bias concat ----------------
__device__ __forceinline__ void cast4(const float* __restrict__ s, u16* __restrict__ d, int i) {
    f32x4 v = *(const f32x4*)(s + (size_t)i * 4);
    u16x4 o;
    o[0] = f2bf(v[0]); o[1] = f2bf(v[1]); o[2] = f2bf(v[2]); o[3] = f2bf(v[3]);
    *(u16x4*)(d + (size_t)i * 4) = o;
}

__global__ __launch_bounds__(256) void prep(const float* __restrict__ hs,
                                            const float* __restrict__ Wq, const float* __restrict__ Wk,
                                            const float* __restrict__ Wv, const float* __restrict__ Wd,
                                            const float* __restrict__ bq, const float* __restrict__ bk,
                                            const float* __restrict__ bv,
                                            u16* __restrict__ hsb, u16* __restrict__ wqkvb,
                                            u16* __restrict__ wdb, float* __restrict__ b3) {
    int bid = blockIdx.x, tid = threadIdx.x;
    if (bid < 4096) {
        cast4(hs, hsb, bid * 256 + tid);
    } else if (bid < 5120) {
        cast4(Wq, wqkvb, (bid - 4096) * 256 + tid);
    } else if (bid < 6144) {
        cast4(Wk, wqkvb + HDIM * HDIM, (bid - 5120) * 256 + tid);
    } else if (bid < 7168) {
        cast4(Wv, wqkvb + 2 * HDIM * HDIM, (bid - 6144) * 256 + tid);
    } else if (bid < 8192) {
        cast4(Wd, wdb, (bid - 7168) * 256 + tid);
    } else {
        int i = (bid - 8192) * 256 + tid;
        if (i < 3072) b3[i] = (i < 1024) ? bq[i] : (i < 2048) ? bk[i - 1024] : bv[i - 2048];
    }
}

// ---------------- GEMM: C[M,N] = A[M,K] * Bw[N,K]^T + bias ----------------
template <int MODE>
__global__ __launch_bounds__(256, 2) void gemm_bt(const u16* __restrict__ A, const u16* __restrict__ Bw,
                                                  const float* __restrict__ bias,
                                                  u16* __restrict__ outb, u16* __restrict__ vtout,
                                                  float* __restrict__ outf,
                                                  int Md, int Nd, int Kd) {
    __shared__ alignas(16) u16 As[128 * 32];
    __shared__ alignas(16) u16 Bs[128 * 32];
    const int tid = threadIdx.x;
    const int wave = tid >> 6, lane = tid & 63;
    const int l15 = lane & 15, l4 = lane >> 4;
    const int m0 = blockIdx.y * 128, n0 = blockIdx.x * 128;
    const int wm = wave >> 1, wn = wave & 1;

    f32x4 acc[4][4];
#pragma unroll
    for (int i = 0; i < 4; i++)
#pragma unroll
        for (int j = 0; j < 4; j++) acc[i][j] = (f32x4){0.f, 0.f, 0.f, 0.f};

    for (int k0 = 0; k0 < Kd; k0 += 32) {
#pragma unroll
        for (int i = 0; i < 2; i++) {
            int cc = wave * 2 + i;
            int row = cc * 16 + (lane >> 2);
            int co = (lane & 3) * 8;
            gld_lds16(A + (size_t)(m0 + row) * Kd + k0 + co, &As[cc * 512]);
            gld_lds16(Bw + (size_t)(n0 + row) * Kd + k0 + co, &Bs[cc * 512]);
        }
        __syncthreads();
        bf16x8 af[4], bf[4];
#pragma unroll
        for (int x = 0; x < 4; x++) {
            af[x] = as_bf16(*(const u16x8*)&As[(wm * 64 + x * 16 + l15) * 32 + l4 * 8]);
            bf[x] = as_bf16(*(const u16x8*)&Bs[(wn * 64 + x * 16 + l15) * 32 + l4 * 8]);
        }
#pragma unroll
        for (int mi = 0; mi < 4; mi++)
#pragma unroll
            for (int nj = 0; nj < 4; nj++)
                acc[mi][nj] = __builtin_amdgcn_mfma_f32_16x16x32_bf16(af[mi], bf[nj], acc[mi][nj], 0, 0, 0);
        __syncthreads();
    }

#pragma unroll
    for (int mi = 0; mi < 4; mi++) {
#pragma unroll
        for (int nj = 0; nj < 4; nj++) {
            int coln = n0 + wn * 64 + nj * 16 + l15;
            float bv_ = bias[coln];
            int rowb = m0 + wm * 64 + mi * 16 + l4 * 4;
            if (MODE == 0) {
                int which = coln >> 10, nn = coln & 1023;
                int hh = nn >> 6, dd = nn & 63;
                int bb = rowb >> 11, ss = rowb & 2047;
                if (which < 2) {
#pragma unroll
                    for (int r = 0; r < 4; r++)
                        outb[(size_t)which * QKV_STRIDE + ((size_t)((bb << 4) + hh) * S_LEN + ss + r) * HD + dd] =
                            f2bf(acc[mi][nj][r] + bv_);
                } else {
                    u16x4 o;
#pragma unroll
                    for (int r = 0; r < 4; r++) o[r] = f2bf(acc[mi][nj][r] + bv_);
                    *(u16x4*)(vtout + ((size_t)((bb << 4) + hh) * HD + dd) * S_LEN + ss) = o;
                }
            } else {
#pragma unroll
                for (int r = 0; r < 4; r++)
                    outf[(size_t)(rowb + r) * Nd + coln] = acc[mi][nj][r] + bv_;
            }
        }
    }
}

// ---------------- flash attention v4: barrier-free, KV streamed L2 -> registers ----------------
// grid 1024 x 256 threads (4 waves x 16 q-rows). XCD-aware: each XCD owns 4 heads.
__global__ __launch_bounds__(256, 4) void flash_attn4(const u16* __restrict__ qkv,
                                                      const u16* __restrict__ vt,
                                                      const float* __restrict__ amask,
                                                      u16* __restrict__ ctx) {
    __shared__ float Ml[2048];
    __shared__ alignas(16) u16 Pl[4][1024];

    const int tid = threadIdx.x;
    const int wave = tid >> 6, lane = tid & 63;
    const int l15 = lane & 15, l4 = lane >> 4;
    const int lid = blockIdx.x;
    const int idx = lid >> 3;
    const int bh = (lid & 7) * 4 + (idx >> 5);   // XCD (lid&7) owns heads 4x..4x+3
    const int qt = idx & 31;
    const int b = bh >> 4, h = bh & 15;
    const int qr0 = qt * 64 + wave * 16;

    const u16* qh = qkv + (size_t)bh * (S_LEN * HD);
    const u16* kh = qh + QKV_STRIDE;
    const u16* vth = vt + (size_t)bh * (S_LEN * HD);   // V^T [64][2048]
    u16* pw = &Pl[wave][0];
    const int rsw = (l15 & 7) << 3;

    // mask -> LDS, pre-scaled by log2(e)
    {
        f32x4 m0 = *(const f32x4*)(amask + (size_t)b * S_LEN + tid * 8);
        f32x4 m1 = *(const f32x4*)(amask + (size_t)b * S_LEN + tid * 8 + 4);
#pragma unroll
        for (int j = 0; j < 4; j++) { m0[j] *= LOG2E; m1[j] *= LOG2E; }
        *(f32x4*)&Ml[tid * 8] = m0;
        *(f32x4*)&Ml[tid * 8 + 4] = m1;
    }

    // Q B-fragment (unscaled; scale folded into exp2 fma)
    bf16x8 qf[2];
#pragma unroll
    for (int ks = 0; ks < 2; ks++)
        qf[ks] = as_bf16(*(const u16x8*)(qh + (size_t)(qr0 + l15) * HD + ks * 32 + l4 * 8));

    __syncthreads();   // mask visible (only barrier in the kernel)

    f32x4 acc_o[4];
    float l_run = 0.f;
#pragma unroll
    for (int x = 0; x < 4; x++) acc_o[x] = (f32x4){0.f, 0.f, 0.f, 0.f};
    const f32x4 zed = (f32x4){0.f, 0.f, 0.f, 0.f};

    // K/V register streams: fragment loads are natural 16B global loads
    u16x8 kreg[8], vreg[8];
    auto LOADK = [&](int t) {
        int kv0 = (t & 31) * 64;
#pragma unroll
        for (int ks = 0; ks < 2; ks++)
#pragma unroll
            for (int nj = 0; nj < 4; nj++)
                kreg[ks * 4 + nj] = *(const u16x8*)(kh + ((size_t)(kv0 + nj * 16 + l15) << 6) + ks * 32 + l4 * 8);
    };
    auto LOADV = [&](int t) {
        int kv0 = (t & 31) * 64;
#pragma unroll
        for (int ks = 0; ks < 2; ks++)
#pragma unroll
            for (int dj = 0; dj < 4; dj++)
                vreg[ks * 4 + dj] = *(const u16x8*)(vth + ((size_t)(dj * 16 + l15) << 11) + kv0 + ks * 32 + l4 * 8);
    };

    LOADK(0);
    LOADV(0);

    for (int t = 0; t < 32; ++t) {
        const int kv0 = t * 64;
        // ---- QK^T (swapped): S^T, col=q=l15, row=kv ----
        f32x4 accs[4];
        __builtin_amdgcn_s_setprio(1);
#pragma unroll
        for (int nj = 0; nj < 4; nj++)
            accs[nj] = __builtin_amdgcn_mfma_f32_16x16x32_bf16(as_bf16(kreg[nj]), qf[0], zed, 0, 0, 0);
#pragma unroll
        for (int nj = 0; nj < 4; nj++)
            accs[nj] = __builtin_amdgcn_mfma_f32_16x16x32_bf16(as_bf16(kreg[4 + nj]), qf[1], accs[nj], 0, 0, 0);
        __builtin_amdgcn_s_setprio(0);

        LOADK(t + 1);   // WAR: issues after QK MFMAs read kreg; in flight under softmax+PV

        // ---- softmax: lane owns q=l15, kv = nj*16 + l4*4 + r ----
#pragma unroll
        for (int nj = 0; nj < 4; nj++) {
            f32x4 mk = *(const f32x4*)&Ml[kv0 + nj * 16 + l4 * 4];
            u16x4 o;
#pragma unroll
            for (int r = 0; r < 4; r++) {
                float p = __builtin_amdgcn_exp2f(accs[nj][r] * QKSCL + mk[r]);
                l_run += p;
                o[r] = f2bf(p);
            }
            *(u16x4*)&pw[l15 * 64 + ((nj * 16 + l4 * 4) ^ rsw)] = o;
        }

        // ---- PV (swapped): O^T += V^T * P^T ----
        __builtin_amdgcn_s_setprio(1);
#pragma unroll
        for (int ks = 0; ks < 2; ks++) {
            int kvoff = ks * 32 + l4 * 8;
            bf16x8 pf = as_bf16(*(const u16x8*)&pw[l15 * 64 + (kvoff ^ rsw)]);
#pragma unroll
            for (int dj = 0; dj < 4; dj++)
                acc_o[dj] = __builtin_amdgcn_mfma_f32_16x16x32_bf16(as_bf16(vreg[ks * 4 + dj]), pf, acc_o[dj], 0, 0, 0);
        }
        __builtin_amdgcn_s_setprio(0);

        LOADV(t + 1);   // WAR: issues after PV MFMAs read vreg; in flight under next QK
    }

    // epilogue: per-lane row-sum (q=l15), reduce over l4 groups
    float l = l_run;
    l += __shfl_xor(l, 16);
    l += __shfl_xor(l, 32);
    float inv = 1.0f / l;
    u16* cp = ctx + ((size_t)b * S_LEN + qr0 + l15) * HDIM + h * HD + l4 * 4;
#pragma unroll
    for (int dj = 0; dj < 4; dj++) {
        u16x4 o;
#pragma unroll
        for (int r = 0; r < 4; r++) o[r] = f2bf(acc_o[dj][r] * inv);
        *(u16x4*)(cp + dj * 16) = o;
    }
}

// ---------------- residual + layernorm ----------------
__global__ __launch_bounds__(256) void resid_ln(const float* __restrict__ hs, const float* __restrict__ proj,
                                                const float* __restrict__ g, const float* __restrict__ be,
                                                float* __restrict__ out) {
    int row = blockIdx.x, tid = threadIdx.x;
    int base = row * HDIM + tid * 4;
    f32x4 a = *(const f32x4*)(hs + base);
    f32x4 p = *(const f32x4*)(proj + base);
    f32x4 x = a + p;
    float s = x[0] + x[1] + x[2] + x[3];
    float sq = x[0] * x[0] + x[1] * x[1] + x[2] * x[2] + x[3] * x[3];
#pragma unroll
    for (int m = 1; m < 64; m <<= 1) {
        s += __shfl_xor(s, m);
        sq += __shfl_xor(sq, m);
    }
    __shared__ float red[8];
    int wave = tid >> 6, lane = tid & 63;
    if (lane == 0) { red[wave] = s; red[4 + wave] = sq; }
    __syncthreads();
    s = red[0] + red[1] + red[2] + red[3];
    sq = red[4] + red[5] + red[6] + red[7];
    float mean = s * (1.0f / 1024.0f);
    float var = sq * (1.0f / 1024.0f) - mean * mean;
    float rstd = rsqrtf(fmaxf(var, 0.f) + 1e-12f);
    f32x4 gg = *(const f32x4*)(g + tid * 4);
    f32x4 bb = *(const f32x4*)(be + tid * 4);
    f32x4 o;
#pragma unroll
    for (int j = 0; j < 4; j++) o[j] = (x[j] - mean) * rstd * gg[j] + bb[j];
    *(f32x4*)(out + base) = o;
}

extern "C" void kernel_launch(void* const* d_in, const int* in_sizes, int n_in,
                              void* d_out, int out_size, void* d_ws, size_t ws_size,
                              hipStream_t stream) {
    const float* hs    = (const float*)d_in[0];
    const float* amask = (const float*)d_in[1];
    const float* Wq    = (const float*)d_in[2];
    const float* bq    = (const float*)d_in[3];
    const float* Wk    = (const float*)d_in[4];
    const float* bk    = (const float*)d_in[5];
    const float* Wv    = (const float*)d_in[6];
    const float* bv    = (const float*)d_in[7];
    const float* Wd    = (const float*)d_in[8];
    const float* bd    = (const float*)d_in[9];
    const float* gamma = (const float*)d_in[10];
    const float* beta  = (const float*)d_in[11];

    char* ws = (char*)d_ws;
    u16*   hsb   = (u16*)(ws);                       // 8 MB: hs bf16 [4096][1024]
    u16*   Wqkvb = (u16*)(ws + ((size_t)8 << 20));   // 6 MB: [3072][1024]
    u16*   Wdb   = (u16*)(ws + ((size_t)14 << 20));  // 2 MB
    u16*   qkv   = (u16*)(ws + ((size_t)16 << 20));  // q,k planes [bh][s][d]; plane 2 = V^T [bh][d][s]
    u16*   vt    = qkv + 2 * (size_t)QKV_STRIDE;
    u16*   ctx   = (u16*)(ws + ((size_t)40 << 20));  // 8 MB: [4096][1024]
    float* proj  = (float*)(ws + ((size_t)48 << 20));// 16 MB
    float* b3    = (float*)(ws + ((size_t)64 << 20));// 12 KB

    prep<<<8204, 256, 0, stream>>>(hs, Wq, Wk, Wv, Wd, bq, bk, bv, hsb, Wqkvb, Wdb, b3);

    // QKV projection: [4096,1024] x [3072,1024]^T ; V written transposed
    gemm_bt<0><<<dim3(24, 32), 256, 0, stream>>>(hsb, Wqkvb, b3, qkv, vt, nullptr, MTOK, 3072, HDIM);

    // attention
    flash_attn4<<<1024, 256, 0, stream>>>(qkv, vt, amask, ctx);

    // output projection: [4096,1024] x [1024,1024]^T -> f32
    gemm_bt<1><<<dim3(8, 32), 256, 0, stream>>>(ctx, Wdb, bd, nullptr, nullptr, proj, MTOK, HDIM, HDIM);

    // residual + layernorm
    resid_ln<<<MTOK, 256, 0, stream>>>(hs, proj, gamma, beta, (float*)d_out);
}

// Round 5
// 128.437 us; speedup vs baseline: 2.4724x; 2.4724x over previous
//
#include <hip/hip_runtime.h>

typedef unsigned short u16;
typedef __attribute__((ext_vector_type(4))) unsigned short u16x4;
typedef __attribute__((ext_vector_type(8))) unsigned short u16x8;
typedef __attribute__((ext_vector_type(8))) __bf16 bf16x8;
typedef __attribute__((ext_vector_type(4))) float f32x4;

#define S_LEN 2048
#define HDIM 1024
#define NHEAD 16
#define HD 64
#define MTOK 4096            // B*S
#define QKV_STRIDE 4194304   // elements per q/k/v plane
#define LOG2E 1.44269504089f
#define QKSCL (0.125f * 1.44269504089f)

__device__ __forceinline__ float bf2f(u16 h) {
    unsigned u = ((unsigned)h) << 16;
    return __builtin_bit_cast(float, u);
}
__device__ __forceinline__ u16 f2bf(float f) {
    return __builtin_bit_cast(u16, (__bf16)f);   // native v_cvt, RNE
}
__device__ __forceinline__ bf16x8 as_bf16(u16x8 u) {
    union { u16x8 a; bf16x8 b; } c; c.a = u; return c.b;
}
__device__ __forceinline__ void gld_lds16(const u16* g, u16* l) {
    __builtin_amdgcn_global_load_lds((const __attribute__((address_space(1))) u16*)g,
                                     (__attribute__((address_space(3))) u16*)l, 16, 0, 0);
}

// ---------------- fused preprocessing: casts + bias concat ----------------
__device__ __forceinline__ void cast4(const float* __restrict__ s, u16* __restrict__ d, int i) {
    f32x4 v = *(const f32x4*)(s + (size_t)i * 4);
    u16x4 o;
    o[0] = f2bf(v[0]); o[1] = f2bf(v[1]); o[2] = f2bf(v[2]); o[3] = f2bf(v[3]);
    *(u16x4*)(d + (size_t)i * 4) = o;
}

__global__ __launch_bounds__(256) void prep(const float* __restrict__ hs,
                                            const float* __restrict__ Wq, const float* __restrict__ Wk,
                                            const float* __restrict__ Wv, const float* __restrict__ Wd,
                                            const float* __restrict__ bq, const float* __restrict__ bk,
                                            const float* __restrict__ bv,
                                            u16* __restrict__ hsb, u16* __restrict__ wqkvb,
                                            u16* __restrict__ wdb, float* __restrict__ b3) {
    int bid = blockIdx.x, tid = threadIdx.x;
    if (bid < 4096) {
        cast4(hs, hsb, bid * 256 + tid);
    } else if (bid < 5120) {
        cast4(Wq, wqkvb, (bid - 4096) * 256 + tid);
    } else if (bid < 6144) {
        cast4(Wk, wqkvb + HDIM * HDIM, (bid - 5120) * 256 + tid);
    } else if (bid < 7168) {
        cast4(Wv, wqkvb + 2 * HDIM * HDIM, (bid - 6144) * 256 + tid);
    } else if (bid < 8192) {
        cast4(Wd, wdb, (bid - 7168) * 256 + tid);
    } else {
        int i = (bid - 8192) * 256 + tid;
        if (i < 3072) b3[i] = (i < 1024) ? bq[i] : (i < 2048) ? bk[i - 1024] : bv[i - 2048];
    }
}

// ---------------- GEMM: C[M,N] = A[M,K] * Bw[N,K]^T + bias ----------------
// 2-phase pipeline: dbuf LDS, stage-next before compute, counted vmcnt, raw barriers.
template <int MODE>
__global__ __launch_bounds__(256, 3) void gemm_bt(const u16* __restrict__ A, const u16* __restrict__ Bw,
                                                  const float* __restrict__ bias,
                                                  u16* __restrict__ outb, u16* __restrict__ vtout,
                                                  float* __restrict__ outf,
                                                  int Md, int Nd, int Kd) {
    __shared__ alignas(16) u16 As[2][128 * 32];
    __shared__ alignas(16) u16 Bs[2][128 * 32];
    const int tid = threadIdx.x;
    const int wave = tid >> 6, lane = tid & 63;
    const int l15 = lane & 15, l4 = lane >> 4;
    const int m0 = blockIdx.y * 128, n0 = blockIdx.x * 128;
    const int wm = wave >> 1, wn = wave & 1;

    const int cc0 = wave * 2;
    const int srow = lane >> 2;          // 0..15
    const int sco = (lane & 3) * 8;      // 0,8,16,24

    f32x4 acc[4][4];
#pragma unroll
    for (int i = 0; i < 4; i++)
#pragma unroll
        for (int j = 0; j < 4; j++) acc[i][j] = (f32x4){0.f, 0.f, 0.f, 0.f};

    auto STAGE = [&](int k0, int buf) {
#pragma unroll
        for (int i = 0; i < 2; i++) {
            int cc = cc0 + i;
            int row = cc * 16 + srow;
            gld_lds16(A + (size_t)(m0 + row) * Kd + k0 + sco, &As[buf][cc * 512]);
            gld_lds16(Bw + (size_t)(n0 + row) * Kd + k0 + sco, &Bs[buf][cc * 512]);
        }
    };

    const int nt = Kd >> 5;
    STAGE(0, 0);
    for (int t = 0; t < nt; ++t) {
        __builtin_amdgcn_s_barrier();                       // all waves done computing t-1
        if (t + 1 < nt) {
            STAGE((t + 1) << 5, (t + 1) & 1);
            asm volatile("s_waitcnt vmcnt(4)" ::: "memory");   // tile t's 4 loads landed
        } else {
            asm volatile("s_waitcnt vmcnt(0)" ::: "memory");
        }
        __builtin_amdgcn_s_barrier();                       // tile t visible to all
        const u16* as = &As[t & 1][0];
        const u16* bs = &Bs[t & 1][0];
        bf16x8 af[4], bf[4];
#pragma unroll
        for (int x = 0; x < 4; x++) {
            af[x] = as_bf16(*(const u16x8*)&as[(wm * 64 + x * 16 + l15) * 32 + l4 * 8]);
            bf[x] = as_bf16(*(const u16x8*)&bs[(wn * 64 + x * 16 + l15) * 32 + l4 * 8]);
        }
        __builtin_amdgcn_s_setprio(1);
#pragma unroll
        for (int mi = 0; mi < 4; mi++)
#pragma unroll
            for (int nj = 0; nj < 4; nj++)
                acc[mi][nj] = __builtin_amdgcn_mfma_f32_16x16x32_bf16(af[mi], bf[nj], acc[mi][nj], 0, 0, 0);
        __builtin_amdgcn_s_setprio(0);
    }

#pragma unroll
    for (int mi = 0; mi < 4; mi++) {
#pragma unroll
        for (int nj = 0; nj < 4; nj++) {
            int coln = n0 + wn * 64 + nj * 16 + l15;
            float bv_ = bias[coln];
            int rowb = m0 + wm * 64 + mi * 16 + l4 * 4;
            if (MODE == 0) {
                int which = coln >> 10, nn = coln & 1023;
                int hh = nn >> 6, dd = nn & 63;
                int bb = rowb >> 11, ss = rowb & 2047;
                if (which < 2) {
#pragma unroll
                    for (int r = 0; r < 4; r++)
                        outb[(size_t)which * QKV_STRIDE + ((size_t)((bb << 4) + hh) * S_LEN + ss + r) * HD + dd] =
                            f2bf(acc[mi][nj][r] + bv_);
                } else {
                    u16x4 o;
#pragma unroll
                    for (int r = 0; r < 4; r++) o[r] = f2bf(acc[mi][nj][r] + bv_);
                    *(u16x4*)(vtout + ((size_t)((bb << 4) + hh) * HD + dd) * S_LEN + ss) = o;
                }
            } else {
#pragma unroll
                for (int r = 0; r < 4; r++)
                    outf[(size_t)(rowb + r) * Nd + coln] = acc[mi][nj][r] + bv_;
            }
        }
    }
}

// ---------------- flash attention v5: v3 structure, 52KB LDS -> 3 blocks/CU ----------------
// 1-D grid 512 blocks, 512 threads (8 waves x 16 q-rows). XCD-aware remap.
__global__ __launch_bounds__(512, 6) void flash_attn5(const u16* __restrict__ qkv,
                                                      const u16* __restrict__ vt,
                                                      const float* __restrict__ amask,
                                                      u16* __restrict__ ctx) {
    __shared__ alignas(16) u16 Kb[2][4096];
    __shared__ alignas(16) u16 Vb[2][4096];
    __shared__ alignas(16) u16 Pl[8][1024];
    __shared__ u16 Mlb[2048];

    const int tid = threadIdx.x;
    const int wave = tid >> 6, lane = tid & 63;
    const int l15 = lane & 15, l4 = lane >> 4;
    // XCD-aware: each XCD (blockIdx.x % 8) owns 4 heads x 16 q-tiles -> KV stays in one L2
    const int lid = blockIdx.x;
    const int idx = lid >> 3;
    const int bh = (lid & 7) * 4 + (idx >> 4);
    const int qx = idx & 15;
    const int b = bh >> 4, h = bh & 15;
    const int qr0 = qx * 128 + wave * 16;

    const u16* qh = qkv + (size_t)bh * (S_LEN * HD);
    const u16* kh = qh + QKV_STRIDE;
    const u16* vth = vt + (size_t)bh * (S_LEN * HD);   // V^T [64][2048]
    u16* pw = &Pl[wave][0];

    // mask -> LDS as bf16, pre-scaled by log2(e)
    {
        f32x4 m = *(const f32x4*)(amask + (size_t)b * S_LEN + tid * 4);
        u16x4 mm;
#pragma unroll
        for (int j = 0; j < 4; j++) mm[j] = f2bf(m[j] * LOG2E);
        *(u16x4*)&Mlb[tid * 4] = mm;
    }

    // Q B-fragment (unscaled; scale folded into exp2 fma)
    bf16x8 qf[2];
#pragma unroll
    for (int ks = 0; ks < 2; ks++)
        qf[ks] = as_bf16(*(const u16x8*)(qh + (size_t)(qr0 + l15) * HD + ks * 32 + l4 * 8));

    __syncthreads();   // mask visible; drains vmcnt (clean FIFO before staging)

    // staging addresses (source pre-swizzled, LDS linear)
    const int srow = lane >> 3;
    const int schunk = (lane & 7) ^ srow;
    const int krow = wave * 8 + srow;
    const u16* ksrc = kh + (size_t)krow * HD + schunk * 8;
    const u16* vsrc = vth + (size_t)krow * S_LEN + schunk * 8;

    f32x4 acc_o[4];
    float l_run = 0.f;
#pragma unroll
    for (int x = 0; x < 4; x++) acc_o[x] = (f32x4){0.f, 0.f, 0.f, 0.f};

    auto STAGE = [&](int T, int buf) {
        gld_lds16(ksrc + (size_t)T * 64 * HD, &Kb[buf][wave * 512]);
        gld_lds16(vsrc + T * 64, &Vb[buf][wave * 512]);
    };

    auto tile = [&](int t, int buf) {
        const u16* kb = &Kb[buf][0];
        const u16* vb = &Vb[buf][0];
        // QK^T swapped: S^T tile, col=q=l15, row=kv
        f32x4 accs[4];
#pragma unroll
        for (int nj = 0; nj < 4; nj++) accs[nj] = (f32x4){0.f, 0.f, 0.f, 0.f};
        __builtin_amdgcn_s_setprio(1);
#pragma unroll
        for (int ks = 0; ks < 2; ks++) {
            bf16x8 kf[4];
#pragma unroll
            for (int nj = 0; nj < 4; nj++) {
                int n = nj * 16 + l15;
                kf[nj] = as_bf16(*(const u16x8*)&kb[n * 64 + ((ks * 32 + l4 * 8) ^ ((n & 7) << 3))]);
            }
#pragma unroll
            for (int nj = 0; nj < 4; nj++)
                accs[nj] = __builtin_amdgcn_mfma_f32_16x16x32_bf16(kf[nj], qf[ks], accs[nj], 0, 0, 0);
        }
        __builtin_amdgcn_s_setprio(0);
        // softmax: each lane owns q=l15, kv = nj*16+l4*4+r (4 consecutive kv)
        const int kv0 = t * 64;
        const int rsw = (l15 & 7) << 3;
#pragma unroll
        for (int nj = 0; nj < 4; nj++) {
            u16x4 mraw = *(const u16x4*)&Mlb[kv0 + nj * 16 + l4 * 4];
            u16x4 o;
#pragma unroll
            for (int r = 0; r < 4; r++) {
                float p = __builtin_amdgcn_exp2f(accs[nj][r] * QKSCL + bf2f(mraw[r]));
                l_run += p;
                o[r] = f2bf(p);
            }
            *(u16x4*)&pw[l15 * 64 + ((nj * 16 + l4 * 4) ^ rsw)] = o;
        }
        // PV swapped: O^T = V^T * P^T
        __builtin_amdgcn_s_setprio(1);
#pragma unroll
        for (int ks = 0; ks < 2; ks++) {
            int kvoff = ks * 32 + l4 * 8;
            bf16x8 pf = as_bf16(*(const u16x8*)&pw[l15 * 64 + (kvoff ^ rsw)]);
            bf16x8 vf[4];
#pragma unroll
            for (int dj = 0; dj < 4; dj++) {
                int d = dj * 16 + l15;
                vf[dj] = as_bf16(*(const u16x8*)&vb[d * 64 + (kvoff ^ ((d & 7) << 3))]);
            }
#pragma unroll
            for (int dj = 0; dj < 4; dj++)
                acc_o[dj] = __builtin_amdgcn_mfma_f32_16x16x32_bf16(vf[dj], pf, acc_o[dj], 0, 0, 0);
        }
        __builtin_amdgcn_s_setprio(0);
    };

    STAGE(0, 0);
    for (int t = 0; t < 32; ++t) {
        __builtin_amdgcn_s_barrier();                       // all waves done computing t-1
        if (t + 1 < 32) {
            STAGE(t + 1, (t + 1) & 1);
            asm volatile("s_waitcnt vmcnt(2)" ::: "memory");   // tile t's 2 loads landed
        } else {
            asm volatile("s_waitcnt vmcnt(0)" ::: "memory");
        }
        __builtin_amdgcn_s_barrier();                       // tile t visible to all
        tile(t, t & 1);
    }

    // epilogue: per-lane scalar row-sum (q = l15), reduce over l4 groups
    float l = l_run;
    l += __shfl_xor(l, 16);
    l += __shfl_xor(l, 32);
    float inv = 1.0f / l;
    u16* cp = ctx + ((size_t)b * S_LEN + qr0 + l15) * HDIM + h * HD + l4 * 4;
#pragma unroll
    for (int dj = 0; dj < 4; dj++) {
        u16x4 o;
#pragma unroll
        for (int r = 0; r < 4; r++) o[r] = f2bf(acc_o[dj][r] * inv);
        *(u16x4*)(cp + dj * 16) = o;
    }
}

// ---------------- residual + layernorm ----------------
__global__ __launch_bounds__(256) void resid_ln(const float* __restrict__ hs, const float* __restrict__ proj,
                                                const float* __restrict__ g, const float* __restrict__ be,
                                                float* __restrict__ out) {
    int row = blockIdx.x, tid = threadIdx.x;
    int base = row * HDIM + tid * 4;
    f32x4 a = *(const f32x4*)(hs + base);
    f32x4 p = *(const f32x4*)(proj + base);
    f32x4 x = a + p;
    float s = x[0] + x[1] + x[2] + x[3];
    float sq = x[0] * x[0] + x[1] * x[1] + x[2] * x[2] + x[3] * x[3];
#pragma unroll
    for (int m = 1; m < 64; m <<= 1) {
        s += __shfl_xor(s, m);
        sq += __shfl_xor(sq, m);
    }
    __shared__ float red[8];
    int wave = tid >> 6, lane = tid & 63;
    if (lane == 0) { red[wave] = s; red[4 + wave] = sq; }
    __syncthreads();
    s = red[0] + red[1] + red[2] + red[3];
    sq = red[4] + red[5] + red[6] + red[7];
    float mean = s * (1.0f / 1024.0f);
    float var = sq * (1.0f / 1024.0f) - mean * mean;
    float rstd = rsqrtf(fmaxf(var, 0.f) + 1e-12f);
    f32x4 gg = *(const f32x4*)(g + tid * 4);
    f32x4 bb = *(const f32x4*)(be + tid * 4);
    f32x4 o;
#pragma unroll
    for (int j = 0; j < 4; j++) o[j] = (x[j] - mean) * rstd * gg[j] + bb[j];
    *(f32x4*)(out + base) = o;
}

extern "C" void kernel_launch(void* const* d_in, const int* in_sizes, int n_in,
                              void* d_out, int out_size, void* d_ws, size_t ws_size,
                              hipStream_t stream) {
    const float* hs    = (const float*)d_in[0];
    const float* amask = (const float*)d_in[1];
    const float* Wq    = (const float*)d_in[2];
    const float* bq    = (const float*)d_in[3];
    const float* Wk    = (const float*)d_in[4];
    const float* bk    = (const float*)d_in[5];
    const float* Wv    = (const float*)d_in[6];
    const float* bv    = (const float*)d_in[7];
    const float* Wd    = (const float*)d_in[8];
    const float* bd    = (const float*)d_in[9];
    const float* gamma = (const float*)d_in[10];
    const float* beta  = (const float*)d_in[11];

    char* ws = (char*)d_ws;
    u16*   hsb   = (u16*)(ws);                       // 8 MB: hs bf16 [4096][1024]
    u16*   Wqkvb = (u16*)(ws + ((size_t)8 << 20));   // 6 MB: [3072][1024]
    u16*   Wdb   = (u16*)(ws + ((size_t)14 << 20));  // 2 MB
    u16*   qkv   = (u16*)(ws + ((size_t)16 << 20));  // q,k planes [bh][s][d]; plane 2 = V^T [bh][d][s]
    u16*   vt    = qkv + 2 * (size_t)QKV_STRIDE;
    u16*   ctx   = (u16*)(ws + ((size_t)40 << 20));  // 8 MB: [4096][1024]
    float* proj  = (float*)(ws + ((size_t)48 << 20));// 16 MB
    float* b3    = (float*)(ws + ((size_t)64 << 20));// 12 KB

    prep<<<8204, 256, 0, stream>>>(hs, Wq, Wk, Wv, Wd, bq, bk, bv, hsb, Wqkvb, Wdb, b3);

    // QKV projection: [4096,1024] x [3072,1024]^T ; V written transposed
    gemm_bt<0><<<dim3(24, 32), 256, 0, stream>>>(hsb, Wqkvb, b3, qkv, vt, nullptr, MTOK, 3072, HDIM);

    // attention
    flash_attn5<<<512, 512, 0, stream>>>(qkv, vt, amask, ctx);

    // output projection: [4096,1024] x [1024,1024]^T -> f32
    gemm_bt<1><<<dim3(8, 32), 256, 0, stream>>>(ctx, Wdb, bd, nullptr, nullptr, proj, MTOK, HDIM, HDIM);

    // residual + layernorm
    resid_ln<<<MTOK, 256, 0, stream>>>(hs, proj, gamma, beta, (float*)d_out);
}